// Round 20
// baseline (7203.133 us; speedup 1.0000x reference)
//
#include <hip/hip_runtime.h>

// LSTMAutoEncoder: B=64, T=512, H=512, F=32.
// Dead-code: only encoder L0 (final h,c) and decoder L0 feed the output:
//   out[:, t, :] = h_dec0_before_step(511-t) @ W_out^T + b_out
// -> 1024 sequential cell steps; batch in 8 pods of 8 rows x 32 blocks.
//
// Round 20 = round 19 (best, 5.54ms) + IN-WAVE PRE-REDUCE:
// within wave w, lanes (kap,gt) with equal gt differ in lane bits 4,5 ->
// two shfl_xor(16/32) rounds sum the wave's 4 K-slice partials in-register
// BEFORE the barrier. Gr shrinks 16 -> 4 planes (one per wave): writes 4x
// fewer (lanes<16 only), post-BAR reduce reads 16 -> 4 ds_read_b128.
// Gather/issue schedule untouched (law, 4x confirmed: issue timing must
// track producer cadence; any change to it has lost).

#define TT   512
#define HH   512
#define FF   32
#define KP   548              // U row stride (floats): 512 h + 32 x + pad
#define PODS 8
#define BT   8                // batch rows per pod
#define GBLK 32               // blocks per pod
#define JT   16               // hidden indices per block
#define NTHR 256
#define NBLK (PODS * GBLK)
#define GRS  68               // Gr batch-row stride (64 gates + 4 pad, 16B-aligned)
#define GPL  (BT * GRS + 8)   // 552: per-plane stride
#define GRF  (4 * GPL)        // 2208 floats per parity (4 planes, one per wave)
#define U_FLOATS  (BT * KP)   // 4384
#define OP3F 32               // [4 waves][8 rows] out-proj partials per slot
#define LDS_FLOATS (U_FLOATS + 2 * GRF + 3 * OP3F)   // 8896 (35.6 KB)
#define LDS_BYTES  (LDS_FLOATS * 4)
#define PUB_U32  (2 * PODS * BT * HH)   // 65536 u32 (256 KB in d_ws)

typedef float f4v __attribute__((ext_vector_type(4)));
typedef float f2v __attribute__((ext_vector_type(2)));
typedef unsigned long long u64;
typedef unsigned int u32;

__device__ __forceinline__ float sigmf(float x)    { return 1.f / (1.f + __expf(-x)); }
__device__ __forceinline__ float tanhfast(float x) { return 1.f - 2.f / (__expf(2.f * x) + 1.f); }

// Thread (w, kap, gt) owns, for every chunk q=0..7, cols [128w+16q+4kap, +4)
// of the 4 gate rows {m*HH + j0 + gt} plus x-cols {8w+2kap, +1}. Packed f2v.
__device__ __forceinline__ void load_w(
    const float* __restrict__ Wih, const float* __restrict__ Whh,
    const float* __restrict__ bih, const float* __restrict__ bhh,
    int j0, int w, int kap, int gt,
    f2v w01[4][8], f2v w23[4][8], f2v wxv[4], float bias[4])
{
  #pragma unroll
  for (int m = 0; m < 4; ++m) {
    const int g = m * HH + j0 + gt;
    #pragma unroll
    for (int q = 0; q < 8; ++q) {
      const f4v tw = *(const f4v*)&Whh[g * HH + w * 128 + q * 16 + kap * 4];
      f2v a; a[0] = tw[0]; a[1] = tw[1]; w01[m][q] = a;
      f2v b; b[0] = tw[2]; b[1] = tw[3]; w23[m][q] = b;
    }
    wxv[m]  = *(const f2v*)&Wih[g * FF + w * 8 + kap * 2];
    bias[m] = bih[g] + bhh[g];
  }
}

__global__ void init_ws_kernel(u32* pub) {
  const int i = blockIdx.x * blockDim.x + threadIdx.x;
  if (i < PUB_U32) pub[i] = 0u;   // h = 0.0f, tag byte = 0 (both parities)
}

#define LDU64(P) __hip_atomic_load((P), __ATOMIC_RELAXED, __HIP_MEMORY_SCOPE_AGENT)

// Issue chunk Q's single u64 load (2 tagged u32 cols 16Q+2sub, +1) from base GP.
#define ISSUE(Q, GP) v[Q] = LDU64((const u64*)((GP) + 16 * (Q)))

// Wait chunk Q fresh (both halves' tag byte == tg), fast retry (sleep after 2
// rounds), strip tags, stage both cols with one 8B LDS write.
#define WAITCH(Q) do {                                                         \
    unsigned lo_ = (unsigned)v[Q], hi_ = (unsigned)(v[Q] >> 32);               \
    int tries = 0;                                                             \
    while ((lo_ & 255u) != tg || (hi_ & 255u) != tg) {                         \
      if (++tries > 2) __builtin_amdgcn_s_sleep(1);                            \
      v[Q] = LDU64((const u64*)(gp + 16 * (Q)));                               \
      lo_ = (unsigned)v[Q]; hi_ = (unsigned)(v[Q] >> 32);                      \
    }                                                                          \
    float2 st_;                                                                \
    st_.x = __uint_as_float(lo_ & ~255u);                                      \
    st_.y = __uint_as_float(hi_ & ~255u);                                      \
    *(float2*)&Us[16 * (Q)] = st_;                                             \
  } while (0)

// FMA on chunk Q: 8 rows x 4 cols x 4 gate types, packed float2 (pk_fma).
#define FMACHUNK(Q) do {                                                       \
    asm volatile("" ::: "memory");                                             \
    _Pragma("unroll")                                                          \
    for (int b = 0; b < 8; ++b) {                                              \
      const f4v u = *(const f4v*)&U[b * KP + w * 128 + 16 * (Q) + 4 * kap];    \
      f2v u01; u01[0] = u[0]; u01[1] = u[1];                                   \
      f2v u23; u23[0] = u[2]; u23[1] = u[3];                                   \
      _Pragma("unroll")                                                        \
      for (int m = 0; m < 4; ++m)                                              \
        acc2[m][b] += u01 * w01[m][Q] + u23 * w23[m][Q];                       \
    }                                                                          \
  } while (0)

__global__ void __launch_bounds__(NTHR, 1)
lstm_ae_kernel(const float* __restrict__ x,
               const float* __restrict__ eWih, const float* __restrict__ eWhh,
               const float* __restrict__ ebih, const float* __restrict__ ebhh,
               const float* __restrict__ dWih, const float* __restrict__ dWhh,
               const float* __restrict__ dbih, const float* __restrict__ dbhh,
               const float* __restrict__ Wo,  const float* __restrict__ bo,
               float* __restrict__ out, u32* __restrict__ pub)
{
  extern __shared__ float lds[];
  float* U   = lds;                      // [BT][KP]     h | x_t (wave-private cols)
  float* Gr  = lds + U_FLOATS;           // [2][4][GPL]  wave-combined partials
  float* OP3 = lds + U_FLOATS + 2 * GRF; // [3][4][8]    out-proj partials (mod-3)

  const int tid = threadIdx.x;
  const int blk = blockIdx.x;
  const int pod = blk & (PODS - 1);
  const int gb  = blk >> 3;          // 0..31 within pod
  const int b0  = pod * BT;
  const int j0  = gb * JT;

  const int w    = tid >> 6;         // wave 0..3: owns h cols [128w,128w+128)
  const int lane = tid & 63;
  const int row  = lane >> 3;        // batch row 0..7
  const int sub  = lane & 7;         // col-pair sub-offset within chunk

  const int ks  = tid >> 4;          // K-slice id 0..15
  const int kap = ks & 3;            // chunk-column group 0..3
  const int gt  = tid & 15;          // hidden index within block

  // Update mapping (static across steps -> c stays in a register).
  const bool upd = tid < BT * JT;            // waves 0-1
  const int  ub  = tid >> 4, ujl = tid & 15;
  float c_reg = 0.f;

  f2v   w01[4][8], w23[4][8], wxv[4];
  float bias[4];
  load_w(eWih, eWhh, ebih, ebhh, j0, w, kap, gt, w01, w23, wxv, bias);

  // Gather state persists across iterations (early-issued chunks 0-3).
  u64 v[8];
  {
    const u32* gp0 = pub + (size_t)pod * (BT * HH) + row * HH + 128 * w + 2 * sub;
    ISSUE(0, gp0); ISSUE(1, gp0); ISSUE(2, gp0); ISSUE(3, gp0);
  }

  #pragma unroll 1
  for (int phase = 0; phase < 2; ++phase) {
    #pragma unroll 1
    for (int step = 0; step < TT; ++step) {
      const int s = phase * TT + step;       // global step 0..1023
      const unsigned tg = (unsigned)(s & 255);
      const int t = phase ? (TT - 1 - step) : step;
      const u32* prd = pub + (size_t)((s & 1) * PODS + pod) * (BT * HH);
      u32*       pwr = pub + (size_t)(((s + 1) & 1) * PODS + pod) * (BT * HH);
      float* Grp = Gr + (s & 1) * GRF;

      // ---- stage this wave's x slice (latency overlaps first wait) ----
      U[row * KP + HH + w * 8 + sub] =
          x[((size_t)(b0 + row) * TT + t) * FF + w * 8 + sub];

      f2v acc2[4][8];
      #pragma unroll
      for (int m = 0; m < 4; ++m)
        #pragma unroll
        for (int b = 0; b < 8; ++b) {
          f2v z; z[0] = (ks == 0) ? bias[m] : 0.f; z[1] = 0.f;
          acc2[m][b] = z;
        }

      // ---- 8-chunk gather->FMA pipeline (chunks 0-3 issued LAST step;
      // 4-7 issued mid-pipeline = correct producer-cadence spacing) ----
      const u32* gp = prd + row * HH + 128 * w + 2 * sub;
      float*     Us = U + row * KP + 128 * w + 2 * sub;

      WAITCH(0); ISSUE(4, gp); FMACHUNK(0);
      WAITCH(1); ISSUE(5, gp); FMACHUNK(1);
      WAITCH(2); ISSUE(6, gp); FMACHUNK(2);
      WAITCH(3); ISSUE(7, gp); FMACHUNK(3);
      WAITCH(4); FMACHUNK(4);
      WAITCH(5); FMACHUNK(5);
      WAITCH(6); FMACHUNK(6);
      WAITCH(7); FMACHUNK(7);

      // ---- x part (packed) ----
      #pragma unroll
      for (int b = 0; b < 8; ++b) {
        const f2v ux = *(const f2v*)&U[b * KP + HH + w * 8 + 2 * kap];
        #pragma unroll
        for (int m = 0; m < 4; ++m)
          acc2[m][b] += ux * wxv[m];
      }

      // ---- IN-WAVE PRE-REDUCE: sum the wave's 4 K-slices (lane bits 4,5)
      // then lanes<16 write ONE plane per wave (4 gates as aligned f4v) ----
      {
        float* Gw = Grp + w * GPL + gt * 4;
        #pragma unroll
        for (int b = 0; b < 8; ++b) {
          f4v r;
          #pragma unroll
          for (int m = 0; m < 4; ++m) {
            float a = acc2[m][b][0] + acc2[m][b][1];
            a += __shfl_xor(a, 16);
            a += __shfl_xor(a, 32);
            r[m] = a;
          }
          if (lane < 16) *(f4v*)&Gw[b * GRS] = r;
        }
      }
      __syncthreads();   // BAR A (the only barrier): Gr complete

      // ---- reduce 4 wave-planes (f4v reads), activations, update, publish ----
      if (upd) {
        const float* g0 = Grp + ub * GRS + ujl * 4;
        const f4v ga = *(const f4v*)(g0);
        const f4v gb2 = *(const f4v*)(g0 + GPL);
        const f4v gc = *(const f4v*)(g0 + 2 * GPL);
        const f4v gd = *(const f4v*)(g0 + 3 * GPL);
        const float si = ga[0] + gb2[0] + gc[0] + gd[0];
        const float sf = ga[1] + gb2[1] + gc[1] + gd[1];
        const float sg = ga[2] + gb2[2] + gc[2] + gd[2];
        const float so = ga[3] + gb2[3] + gc[3] + gd[3];
        const float c2 = sigmf(sf) * c_reg + sigmf(si) * tanhfast(sg);
        const float h2 = sigmf(so) * tanhfast(c2);
        c_reg = c2;
        // mantissa-tag publish: low byte of the f32 carries (s+1)&255
        const unsigned pk = (__float_as_uint(h2) & ~255u)
                          | ((unsigned)(s + 1) & 255u);
        __hip_atomic_store(&pwr[ub * HH + j0 + ujl], pk,
                           __ATOMIC_RELAXED, __HIP_MEMORY_SCOPE_AGENT);
      }

      // ---- decoder out-projection, POST-barrier (overlaps reduce/publish).
      // Partial over this wave's own 128 U cols (pre-update h(t), faithful),
      // shfl-reduced over sub -> 8 floats/wave into OP3[s%3]; combined one
      // step later (BAR A of s+1 orders the writes; (s+1)%3 != (s-1)%3). ----
      if (phase) {
        const float* wrow = Wo + gb * HH + w * 128 + sub * 16;
        const float* urow = U + row * KP + w * 128 + sub * 16;
        float pj = 0.f;
        #pragma unroll
        for (int k = 0; k < 16; k += 4) {
          const f4v wvv = *(const f4v*)(wrow + k);
          const f4v uvv = *(const f4v*)(urow + k);
          pj += uvv[0] * wvv[0] + uvv[1] * wvv[1] + uvv[2] * wvv[2] + uvv[3] * wvv[3];
        }
        pj += __shfl_xor(pj, 1);
        pj += __shfl_xor(pj, 2);
        pj += __shfl_xor(pj, 4);
        if (sub == 0) OP3[(s % 3) * OP3F + w * 8 + row] = pj;
        // combine PREVIOUS decode step (t_prev = t+1)
        if (step > 0 && tid >= 192 && tid < 200) {
          const int b = tid - 192;
          const float* op = OP3 + ((s - 1) % 3) * OP3F + b;
          const float sm = op[0] + op[8] + op[16] + op[24];
          out[((size_t)(b0 + b) * TT + (t + 1)) * FF + gb] = sm + bo[gb];
        }
      }

      // ---- EARLY ISSUE: chunks 0-3 of step s+1 (next parity = pwr plane). ----
      {
        const u32* gpn = (const u32*)pwr + row * HH + 128 * w + 2 * sub;
        ISSUE(0, gpn); ISSUE(1, gpn); ISSUE(2, gpn); ISSUE(3, gpn);
        asm volatile("" ::: "memory");
      }
    }
    if (phase == 0)  // encoder done: swap register weights to decoder
      load_w(dWih, dWhh, dbih, dbhh, j0, w, kap, gt, w01, w23, wxv, bias);
  }

  // ---- epilogue: combine the final decode step's out-proj (t = 0) ----
  __syncthreads();
  if (tid >= 192 && tid < 200) {
    const int b = tid - 192;
    const float* op = OP3 + ((2 * TT - 1) % 3) * OP3F + b;
    const float sm = op[0] + op[8] + op[16] + op[24];
    out[((size_t)(b0 + b) * TT + 0) * FF + gb] = sm + bo[gb];
  }
}

extern "C" void kernel_launch(void* const* d_in, const int* in_sizes, int n_in,
                              void* d_out, int out_size, void* d_ws, size_t ws_size,
                              hipStream_t stream) {
  const float* x    = (const float*)d_in[0];
  const float* eWih = (const float*)d_in[1];   // enc_Wih0 [2048,32]
  const float* eWhh = (const float*)d_in[2];   // enc_Whh0 [2048,512]
  const float* ebih = (const float*)d_in[3];
  const float* ebhh = (const float*)d_in[4];
  // d_in[5..8] enc layer 1: dead (only feeds dead decoder layer 1)
  const float* dWih = (const float*)d_in[9];   // dec_Wih0
  const float* dWhh = (const float*)d_in[10];  // dec_Whh0
  const float* dbih = (const float*)d_in[11];
  const float* dbhh = (const float*)d_in[12];
  // d_in[13..16] dec layer 1: dead (hB/cB never reach outs)
  const float* Wo   = (const float*)d_in[17];  // [32,512]
  const float* bo   = (const float*)d_in[18];  // [32]
  float* out = (float*)d_out;

  u32* pubbuf = (u32*)d_ws;                    // [2][8][8][512] tagged h (u32)

  hipFuncSetAttribute(reinterpret_cast<const void*>(lstm_ae_kernel),
                      hipFuncAttributeMaxDynamicSharedMemorySize, LDS_BYTES);

  init_ws_kernel<<<dim3((PUB_U32 + NTHR - 1) / NTHR), dim3(NTHR), 0, stream>>>(pubbuf);
  lstm_ae_kernel<<<dim3(NBLK), dim3(NTHR), LDS_BYTES, stream>>>(
      x, eWih, eWhh, ebih, ebhh, dWih, dWhh, dbih, dbhh, Wo, bo,
      out, pubbuf);
}

// Round 21
// 4814.327 us; speedup vs baseline: 1.4962x; 1.4962x over previous
//
#include <hip/hip_runtime.h>

// LSTMAutoEncoder: B=64, T=512, H=512, F=32.
// Dead-code: only encoder L0 (final h,c) and decoder L0 feed the output:
//   out[:, t, :] = h_dec0_before_step(511-t) @ W_out^T + b_out
// -> 1024 sequential cell steps.
//
// Round 21 = round 19 (best, 5.54ms) HALVED for 2-blocks/CU hardware TLP:
// 512 blocks x 256 thr, 16 pods x 4 batch rows, 32 blocks/pod (fan-in
// unchanged), JT=16 hidden/block. __launch_bounds__(256,2) + 44.8KB LDS ->
// exactly 2 blocks/CU resident = 2 waves/SIMD from INDEPENDENT blocks: the
// hardware interleaves block A's barrier/MALL stalls with block B's FMA.
// (r15's software stagger failed by serializing 2 pods through the SAME
// waves; hardware multiplexing of separate blocks adds no fixed cost.)
// Everything else is r19 verbatim-halved: same tag protocol (induction
// carries), same 2-early/2-mid issue cadence, vectorized Gr, OP3 deferral.
// r20's shfl pre-reduce REVERTED (ds_bpermute cost > LDS reduce; 5th law:
// never lengthen the pre-BAR critical path).

#define TT   512
#define HH   512
#define FF   32
#define KP   548              // U row stride (floats): 512 h + 32 x + pad
#define PODS 16
#define BT   4                // batch rows per pod
#define JT   16               // hidden indices per block
#define NTHR 256
#define NBLK 512
#define GRS  68               // Gr batch-row stride (64 gates + 4 pad, 16B-aligned)
#define GPL  (BT * GRS + 8)   // 280: per-ks plane stride
#define GRF  (16 * GPL)       // 4480 floats per parity
#define U_FLOATS  (BT * KP)   // 2192
#define OP3F 16               // [4 waves][4 rows] out-proj partials per slot
#define LDS_FLOATS (U_FLOATS + 2 * GRF + 3 * OP3F)   // 11200 (44.8 KB)
#define PUB_U32  (2 * PODS * BT * HH)   // 65536 u32 (256 KB in d_ws)

typedef float f4v __attribute__((ext_vector_type(4)));
typedef float f2v __attribute__((ext_vector_type(2)));
typedef unsigned long long u64;
typedef unsigned int u32;

__device__ __forceinline__ float sigmf(float x)    { return 1.f / (1.f + __expf(-x)); }
__device__ __forceinline__ float tanhfast(float x) { return 1.f - 2.f / (__expf(2.f * x) + 1.f); }

// Thread (w, kap 0..3, gt 0..15) owns, for every chunk q=0..3 (32 cols each),
// cols [128w + 32q + 8kap, +8) of gate rows {m*HH + j0 + gt} plus x-cols
// {8w+2kap, +1}. 8 cols per (m,q) = two f4v, packed as four f2v.
__device__ __forceinline__ void load_w(
    const float* __restrict__ Wih, const float* __restrict__ Whh,
    const float* __restrict__ bih, const float* __restrict__ bhh,
    int j0, int w, int kap, int gt,
    f2v wa01[4][4], f2v wa23[4][4], f2v wb01[4][4], f2v wb23[4][4],
    f2v wxv[4], float bias[4])
{
  #pragma unroll
  for (int m = 0; m < 4; ++m) {
    const int g = m * HH + j0 + gt;
    #pragma unroll
    for (int q = 0; q < 4; ++q) {
      const float* p = &Whh[g * HH + w * 128 + q * 32 + kap * 8];
      const f4v t0 = *(const f4v*)(p);
      const f4v t1 = *(const f4v*)(p + 4);
      f2v a; a[0] = t0[0]; a[1] = t0[1]; wa01[m][q] = a;
      f2v b; b[0] = t0[2]; b[1] = t0[3]; wa23[m][q] = b;
      f2v c; c[0] = t1[0]; c[1] = t1[1]; wb01[m][q] = c;
      f2v d; d[0] = t1[2]; d[1] = t1[3]; wb23[m][q] = d;
    }
    wxv[m]  = *(const f2v*)&Wih[g * FF + w * 8 + kap * 2];
    bias[m] = bih[g] + bhh[g];
  }
}

__global__ void init_ws_kernel(u32* pub) {
  const int i = blockIdx.x * blockDim.x + threadIdx.x;
  if (i < PUB_U32) pub[i] = 0u;   // h = 0.0f, tag byte = 0 (both parities)
}

#define LDU64(P) __hip_atomic_load((P), __ATOMIC_RELAXED, __HIP_MEMORY_SCOPE_AGENT)

// Issue chunk Q's single u64 load (2 tagged u32 cols 32Q+2sub, +1) from base GP.
#define ISSUE(Q, GP) v[Q] = LDU64((const u64*)((GP) + 32 * (Q)))

// Wait chunk Q fresh (both halves' tag byte == tg), fast retry (sleep after 2
// rounds), strip tags, stage both cols with one 8B LDS write.
#define WAITCH(Q) do {                                                         \
    unsigned lo_ = (unsigned)v[Q], hi_ = (unsigned)(v[Q] >> 32);               \
    int tries = 0;                                                             \
    while ((lo_ & 255u) != tg || (hi_ & 255u) != tg) {                         \
      if (++tries > 2) __builtin_amdgcn_s_sleep(1);                            \
      v[Q] = LDU64((const u64*)(gp + 32 * (Q)));                               \
      lo_ = (unsigned)v[Q]; hi_ = (unsigned)(v[Q] >> 32);                      \
    }                                                                          \
    float2 st_;                                                                \
    st_.x = __uint_as_float(lo_ & ~255u);                                      \
    st_.y = __uint_as_float(hi_ & ~255u);                                      \
    *(float2*)&Us[32 * (Q)] = st_;                                             \
  } while (0)

// FMA on chunk Q: 4 rows x 8 cols x 4 gate types, packed f2v.
#define FMACHUNK(Q) do {                                                       \
    asm volatile("" ::: "memory");                                             \
    _Pragma("unroll")                                                          \
    for (int b = 0; b < 4; ++b) {                                              \
      const float* p = &U[b * KP + w * 128 + 32 * (Q) + 8 * kap];              \
      const f4v u0 = *(const f4v*)(p);                                         \
      const f4v u1 = *(const f4v*)(p + 4);                                     \
      f2v u0a; u0a[0] = u0[0]; u0a[1] = u0[1];                                 \
      f2v u0b; u0b[0] = u0[2]; u0b[1] = u0[3];                                 \
      f2v u1a; u1a[0] = u1[0]; u1a[1] = u1[1];                                 \
      f2v u1b; u1b[0] = u1[2]; u1b[1] = u1[3];                                 \
      _Pragma("unroll")                                                        \
      for (int m = 0; m < 4; ++m)                                              \
        acc2[m][b] += u0a * wa01[m][Q] + u0b * wa23[m][Q]                      \
                    + u1a * wb01[m][Q] + u1b * wb23[m][Q];                     \
    }                                                                          \
  } while (0)

__global__ void __launch_bounds__(NTHR, 2)
lstm_ae_kernel(const float* __restrict__ x,
               const float* __restrict__ eWih, const float* __restrict__ eWhh,
               const float* __restrict__ ebih, const float* __restrict__ ebhh,
               const float* __restrict__ dWih, const float* __restrict__ dWhh,
               const float* __restrict__ dbih, const float* __restrict__ dbhh,
               const float* __restrict__ Wo,  const float* __restrict__ bo,
               float* __restrict__ out, u32* __restrict__ pub)
{
  __shared__ float lds[LDS_FLOATS];
  float* U   = lds;                      // [BT][KP]      h | x_t (wave-private cols)
  float* Gr  = lds + U_FLOATS;           // [2][16][GPL]  K-split partials (parity)
  float* OP3 = lds + U_FLOATS + 2 * GRF; // [3][4][4]     out-proj partials (mod-3)

  const int tid = threadIdx.x;
  const int blk = blockIdx.x;
  const int pod = blk & (PODS - 1);    // 16 pods x 4 rows
  const int gb  = blk >> 4;            // 0..31: hidden slice j0 = gb*16
  const int b0  = pod * BT;
  const int j0  = gb * JT;

  const int w    = tid >> 6;           // wave 0..3: owns h cols [128w,+128)
  const int lane = tid & 63;
  const int row  = lane >> 4;          // staging: batch row 0..3
  const int sub  = lane & 15;          // staging: col-pair offset 0..15

  const int kap = lane >> 4;           // gemm: chunk-col group 0..3
  const int gt  = lane & 15;           // gemm: hidden index within block

  // Update mapping (static across steps -> c stays in a register).
  const bool upd = tid < BT * JT;      // 64 threads
  const int  ub  = tid >> 4, ujl = tid & 15;
  float c_reg = 0.f;

  f2v wa01[4][4], wa23[4][4], wb01[4][4], wb23[4][4], wxv[4];
  float bias[4];
  load_w(eWih, eWhh, ebih, ebhh, j0, w, kap, gt, wa01, wa23, wb01, wb23, wxv, bias);

  // Gather state persists across iterations (chunks 0-1 early-issued).
  u64 v[4];
  {
    const u32* gp0 = pub + (size_t)pod * (BT * HH) + row * HH + 128 * w + 2 * sub;
    ISSUE(0, gp0); ISSUE(1, gp0);
  }

  #pragma unroll 1
  for (int phase = 0; phase < 2; ++phase) {
    #pragma unroll 1
    for (int step = 0; step < TT; ++step) {
      const int s = phase * TT + step;       // global step 0..1023
      const unsigned tg = (unsigned)(s & 255);
      const int t = phase ? (TT - 1 - step) : step;
      const u32* prd = pub + (size_t)((s & 1) * PODS + pod) * (BT * HH);
      u32*       pwr = pub + (size_t)(((s + 1) & 1) * PODS + pod) * (BT * HH);
      float* Grp = Gr + (s & 1) * GRF;

      // ---- stage this wave's x slice (latency overlaps first wait) ----
      if (sub < 8)
        U[row * KP + HH + w * 8 + sub] =
            x[((size_t)(b0 + row) * TT + t) * FF + w * 8 + sub];

      f2v acc2[4][4];
      #pragma unroll
      for (int m = 0; m < 4; ++m)
        #pragma unroll
        for (int b = 0; b < 4; ++b) {
          f2v z; z[0] = ((w | kap) == 0) ? bias[m] : 0.f; z[1] = 0.f;
          acc2[m][b] = z;
        }

      // ---- 4-chunk gather->FMA pipeline (0-1 issued LAST step;
      // 2-3 issued mid-pipeline = proven producer-cadence spacing) ----
      const u32* gp = prd + row * HH + 128 * w + 2 * sub;
      float*     Us = U + row * KP + 128 * w + 2 * sub;

      WAITCH(0); ISSUE(2, gp); FMACHUNK(0);
      WAITCH(1); ISSUE(3, gp); FMACHUNK(1);
      WAITCH(2); FMACHUNK(2);
      WAITCH(3); FMACHUNK(3);

      // ---- x part (packed) ----
      #pragma unroll
      for (int b = 0; b < 4; ++b) {
        const f2v ux = *(const f2v*)&U[b * KP + HH + w * 8 + 2 * kap];
        #pragma unroll
        for (int m = 0; m < 4; ++m)
          acc2[m][b] += ux * wxv[m];
      }
      // ---- Gr write: 4 gates of (b, hidden gt) as one aligned f4v ----
      {
        float* Gw = Grp + (w * 4 + kap) * GPL + gt * 4;
        #pragma unroll
        for (int b = 0; b < 4; ++b) {
          f4v r;
          #pragma unroll
          for (int m = 0; m < 4; ++m) r[m] = acc2[m][b][0] + acc2[m][b][1];
          *(f4v*)&Gw[b * GRS] = r;
        }
      }
      __syncthreads();   // BAR A (the only barrier): Gr complete

      // ---- reduce 16 K-planes (f4v reads), activations, update, publish ----
      if (upd) {
        const float* g0 = Grp + ub * GRS + ujl * 4;
        float si = 0.f, sf = 0.f, sg = 0.f, so = 0.f;
        #pragma unroll
        for (int q = 0; q < 16; ++q) {
          const f4v g = *(const f4v*)(g0 + q * GPL);
          si += g[0]; sf += g[1]; sg += g[2]; so += g[3];
        }
        const float c2 = sigmf(sf) * c_reg + sigmf(si) * tanhfast(sg);
        const float h2 = sigmf(so) * tanhfast(c2);
        c_reg = c2;
        // mantissa-tag publish: low byte of the f32 carries (s+1)&255
        const unsigned pk = (__float_as_uint(h2) & ~255u)
                          | ((unsigned)(s + 1) & 255u);
        __hip_atomic_store(&pwr[ub * HH + j0 + ujl], pk,
                           __ATOMIC_RELAXED, __HIP_MEMORY_SCOPE_AGENT);
      }

      // ---- decoder out-projection, POST-barrier (overlaps reduce/publish).
      // Partial over this wave's own 128 U cols (pre-update h(t), faithful):
      // lane (row, sub) dots 8 cols; shfl-reduce over sub -> 4 floats/wave
      // into OP3[s%3]; combined one step later. ----
      if (phase) {
        const float* wrow = Wo + gb * HH + w * 128 + sub * 8;
        const float* urow = U + row * KP + w * 128 + sub * 8;
        const f4v u0 = *(const f4v*)(urow);
        const f4v u1 = *(const f4v*)(urow + 4);
        const f4v q0 = *(const f4v*)(wrow);
        const f4v q1 = *(const f4v*)(wrow + 4);
        float pj = u0[0]*q0[0] + u0[1]*q0[1] + u0[2]*q0[2] + u0[3]*q0[3]
                 + u1[0]*q1[0] + u1[1]*q1[1] + u1[2]*q1[2] + u1[3]*q1[3];
        pj += __shfl_xor(pj, 1);
        pj += __shfl_xor(pj, 2);
        pj += __shfl_xor(pj, 4);
        pj += __shfl_xor(pj, 8);
        if (sub == 0) OP3[(s % 3) * OP3F + w * 4 + row] = pj;
        // combine PREVIOUS decode step (t_prev = t+1)
        if (step > 0 && tid >= 192 && tid < 196) {
          const int b = tid - 192;
          const float* op = OP3 + ((s - 1) % 3) * OP3F + b;
          const float sm = op[0] + op[4] + op[8] + op[12];
          out[((size_t)(b0 + b) * TT + (t + 1)) * FF + gb] = sm + bo[gb];
        }
      }

      // ---- EARLY ISSUE: chunks 0-1 of step s+1 (next parity = pwr plane). ----
      {
        const u32* gpn = (const u32*)pwr + row * HH + 128 * w + 2 * sub;
        ISSUE(0, gpn); ISSUE(1, gpn);
        asm volatile("" ::: "memory");
      }
    }
    if (phase == 0)  // encoder done: swap register weights to decoder
      load_w(dWih, dWhh, dbih, dbhh, j0, w, kap, gt, wa01, wa23, wb01, wb23, wxv, bias);
  }

  // ---- epilogue: combine the final decode step's out-proj (t = 0) ----
  __syncthreads();
  if (tid >= 192 && tid < 196) {
    const int b = tid - 192;
    const float* op = OP3 + ((2 * TT - 1) % 3) * OP3F + b;
    const float sm = op[0] + op[4] + op[8] + op[12];
    out[((size_t)(b0 + b) * TT + 0) * FF + gb] = sm + bo[gb];
  }
}

extern "C" void kernel_launch(void* const* d_in, const int* in_sizes, int n_in,
                              void* d_out, int out_size, void* d_ws, size_t ws_size,
                              hipStream_t stream) {
  const float* x    = (const float*)d_in[0];
  const float* eWih = (const float*)d_in[1];   // enc_Wih0 [2048,32]
  const float* eWhh = (const float*)d_in[2];   // enc_Whh0 [2048,512]
  const float* ebih = (const float*)d_in[3];
  const float* ebhh = (const float*)d_in[4];
  // d_in[5..8] enc layer 1: dead (only feeds dead decoder layer 1)
  const float* dWih = (const float*)d_in[9];   // dec_Wih0
  const float* dWhh = (const float*)d_in[10];  // dec_Whh0
  const float* dbih = (const float*)d_in[11];
  const float* dbhh = (const float*)d_in[12];
  // d_in[13..16] dec layer 1: dead (hB/cB never reach outs)
  const float* Wo   = (const float*)d_in[17];  // [32,512]
  const float* bo   = (const float*)d_in[18];  // [32]
  float* out = (float*)d_out;

  u32* pubbuf = (u32*)d_ws;                    // [2][16][4][512] tagged h (u32)

  init_ws_kernel<<<dim3((PUB_U32 + NTHR - 1) / NTHR), dim3(NTHR), 0, stream>>>(pubbuf);
  lstm_ae_kernel<<<dim3(NBLK), dim3(NTHR), 0, stream>>>(
      x, eWih, eWhh, ebih, ebhh, dWih, dWhh, dbih, dbhh, Wo, bo,
      out, pubbuf);
}